// Round 9
// baseline (521.712 us; speedup 1.0000x reference)
//
#include <hip/hip_runtime.h>
#include <hip/hip_bf16.h>
#include <math.h>
#include <stdint.h>

#define BT  4096
#define DIM 1024
#define HID 4096
#define NE  8
#define TMX 72   // max active 128-row m-blocks

typedef __attribute__((ext_vector_type(8))) short short8v;
typedef __attribute__((ext_vector_type(4))) float f32x4;
typedef unsigned short ushort_t;

typedef __attribute__((address_space(1))) const void gas_void;
typedef __attribute__((address_space(3))) void las_void;
#define GLOAD_LDS16(g, l) __builtin_amdgcn_global_load_lds((gas_void*)(g), (las_void*)(l), 16, 0, 0)

__device__ inline ushort_t f2bf(float f) {
  __hip_bfloat16 b = __float2bfloat16(f);
  union { __hip_bfloat16 h; ushort_t u; } cv;
  cv.h = b;
  return cv.u;
}

// -------- shared transpose body: src fp32 [E][R][C] -> dst bf16 [E][C][R] ----
__device__ __forceinline__ void transpose_body(
    const float* __restrict__ src, ushort_t* __restrict__ dst,
    int R, int C, int bx, int by, int e, float (*tile)[65]) {
  const float* s = src + (size_t)e * R * C;
  ushort_t* d = dst + (size_t)e * R * C;
  int c0 = bx * 64, r0 = by * 64;
  int t = threadIdx.x;
  int lr = t >> 4;
  int lc4 = (t & 15) * 4;
#pragma unroll
  for (int i = 0; i < 4; i++) {
    int r = lr + 16 * i;
    float4 v = *(const float4*)&s[(size_t)(r0 + r) * C + c0 + lc4];
    tile[r][lc4 + 0] = v.x; tile[r][lc4 + 1] = v.y;
    tile[r][lc4 + 2] = v.z; tile[r][lc4 + 3] = v.w;
  }
  __syncthreads();
  int c = t >> 3, r8 = (t & 7) * 8;
#pragma unroll
  for (int p = 0; p < 2; p++) {
    int cc = c + 32 * p;
    short8v ov;
#pragma unroll
    for (int i = 0; i < 8; i++) ov[i] = (short)f2bf(tile[r8 + i][cc]);
    *(short8v*)&d[(size_t)(c0 + cc) * R + r0 + r8] = ov;
  }
}

// ============================================================================
// Kernel A: prep_router ∥ w1-transpose (independent producers, one grid).
// Grid 12288: id%3==2 -> prep token id/3; else w1t tile 2*(id/3)+(id%3).
// ============================================================================
__global__ __launch_bounds__(256) void k_prep_w1t(
    const float* __restrict__ x, const float* __restrict__ wg,
    ushort_t* __restrict__ xbf, float* __restrict__ logits_out,
    float* __restrict__ probs01, int* __restrict__ assign,
    int* __restrict__ cur, const float* __restrict__ w1,
    ushort_t* __restrict__ wt1) {
  __shared__ __attribute__((aligned(16))) char smem[64 * 65 * 4];
  int id = blockIdx.x;
  int r3 = id % 3;
  if (r3 != 2) {
    int t = 2 * (id / 3) + r3;                 // 0..8191
    int bx = t & 63, by = (t >> 6) & 15, bz = t >> 10;
    transpose_body(w1, wt1, DIM, HID, bx, by, bz, (float(*)[65])smem);
    return;
  }
  int t = id / 3;                              // 0..4095
  int tid = threadIdx.x;
  const float* xr = x + (size_t)t * DIM;
  float4 v = ((const float4*)xr)[tid];
  ushort4 o;
  o.x = f2bf(v.x); o.y = f2bf(v.y); o.z = f2bf(v.z); o.w = f2bf(v.w);
  ((ushort4*)(xbf + (size_t)t * DIM))[tid] = o;

  float vv[4] = {v.x, v.y, v.z, v.w};
  float part[NE];
#pragma unroll
  for (int e = 0; e < NE; e++) part[e] = 0.f;
#pragma unroll
  for (int i = 0; i < 4; i++) {
    const float4* wr = (const float4*)(wg + (size_t)(tid * 4 + i) * NE);
    float4 a = wr[0], b = wr[1];
    part[0] += vv[i] * a.x; part[1] += vv[i] * a.y;
    part[2] += vv[i] * a.z; part[3] += vv[i] * a.w;
    part[4] += vv[i] * b.x; part[5] += vv[i] * b.y;
    part[6] += vv[i] * b.z; part[7] += vv[i] * b.w;
  }
#pragma unroll
  for (int e = 0; e < NE; e++)
    for (int off = 32; off > 0; off >>= 1)
      part[e] += __shfl_xor(part[e], off);

  float (*red)[NE] = (float(*)[NE])smem;
  int lane = tid & 63, wv = tid >> 6;
  if (lane == 0) {
#pragma unroll
    for (int e = 0; e < NE; e++) red[wv][e] = part[e];
  }
  __syncthreads();
  if (tid == 0) {
    float s8[NE];
#pragma unroll
    for (int e = 0; e < NE; e++)
      s8[e] = red[0][e] + red[1][e] + red[2][e] + red[3][e];
    float m = s8[0];
    for (int e = 1; e < NE; e++) m = fmaxf(m, s8[e]);
    float p[NE], s = 0.f;
    for (int e = 0; e < NE; e++) { p[e] = expf(s8[e] - m); s += p[e]; }
    float inv = 1.f / s;
    for (int e = 0; e < NE; e++) p[e] *= inv;
    for (int e = 0; e < NE; e++) logits_out[(size_t)t * NE + e] = s8[e];
    probs01[t * 2 + 0] = p[0];
    probs01[t * 2 + 1] = p[1];
    int b0 = 0;
    for (int e = 1; e < NE; e++) if (p[e] > p[b0]) b0 = e;
    int b1 = (b0 == 0) ? 1 : 0;
    for (int e = 0; e < NE; e++) if (e != b0 && p[e] > p[b1]) b1 = e;
    int pos0 = atomicAdd(&cur[b0], 1);
    assign[b0 * BT + pos0] = t * 2 + 0;
    int pos1 = atomicAdd(&cur[b1], 1);
    assign[b1 * BT + pos1] = t * 2 + 1;
  }
}

// -------- plan: prefix offsets + flattened active 128-row block list --------
__global__ void k_plan(const int* __restrict__ cur, int* __restrict__ segoff,
                       int* __restrict__ blk_e, int* __restrict__ blk_m0) {
  if (threadIdx.x == 0 && blockIdx.x == 0) {
    int s = 0;
    for (int e = 0; e < NE; e++) { segoff[e] = s; s += cur[e]; }
    int t = 0;
    for (int e = 0; e < NE; e++) {
      int mb = (cur[e] + 127) >> 7;
      for (int i = 0; i < mb; i++) { blk_e[t] = e; blk_m0[t] = i << 7; t++; }
    }
    for (; t < TMX; t++) { blk_e[t] = -1; blk_m0[t] = 0; }
  }
}

// ============================================================================
// GEMM core (R7, 3x-verified): 128x128 tile, BK=32, ring-4 LDS = 64 KiB,
// 4 waves (2Mx2N), wave tile 64x64, acc[4][4].  Single barrier per K-tile,
// counted vmcnt (steady 8; tail 8,4,0), XOR swizzle both sides, setprio.
// ============================================================================
#define VM8 asm volatile("s_waitcnt vmcnt(8)" ::: "memory")
#define VM4 asm volatile("s_waitcnt vmcnt(4)" ::: "memory")
#define VM0 asm volatile("s_waitcnt vmcnt(0)" ::: "memory")
#define VMN do {} while (0)

#define TILEK(TB, T, VMX, DOSTG)                                                \
  { short8v bv[4], af[4];                                                       \
    _Pragma("unroll")                                                           \
    for (int n = 0; n < 4; n++)                                                 \
      bv[n] = *(const short8v*)&Bv[TB][wn * 64 + n * 16 + lr][xsw];             \
    _Pragma("unroll")                                                           \
    for (int m = 0; m < 4; m++)                                                 \
      af[m] = *(const short8v*)&A[TB][wm * 64 + m * 16 + lr][xsw];              \
    if (DOSTG) { STAGE((((TB) + 3) & 3), ((T) + 3) * 32); }                     \
    VMX;                                                                        \
    __builtin_amdgcn_s_barrier();                                               \
    __builtin_amdgcn_sched_barrier(0);                                          \
    __builtin_amdgcn_s_setprio(1);                                              \
    _Pragma("unroll")                                                           \
    for (int m = 0; m < 4; m++)                                                 \
      _Pragma("unroll")                                                         \
      for (int n = 0; n < 4; n++)                                               \
        acc[m][n] = __builtin_amdgcn_mfma_f32_16x16x32_bf16(af[m], bv[n],       \
                                                            acc[m][n], 0, 0, 0);\
    __builtin_amdgcn_s_setprio(0); }

// ============================================================================
// Kernel B: gemm1 ∥ w2-transpose (independent; w2t only feeds gemm2).
// Grid 10496 = 2304 gemm1 + 8192 w2t, Bresenham-interleaved so transpose
// blocks co-reside with gemm1 blocks (both paths use the same 64 KiB smem).
// ============================================================================
__global__ __launch_bounds__(256, 2) void k_gemm1_w2t(
    const ushort_t* __restrict__ xbf, const ushort_t* __restrict__ wt1,
    const float* __restrict__ b1,
    const int* __restrict__ assign, const int* __restrict__ cur,
    const int* __restrict__ segoff, const int* __restrict__ blk_e,
    const int* __restrict__ blk_m0, ushort_t* __restrict__ hbuf,
    const float* __restrict__ w2, ushort_t* __restrict__ wt2) {
  __shared__ __attribute__((aligned(16))) char smem[65536];
  const int NG = 32 * TMX;                     // 2304 gemm1 blocks
  const int TOT = NG + 8192;                   // 10496
  int id = blockIdx.x;
  long long a0 = ((long long)id * NG) / TOT;
  long long a1 = ((long long)(id + 1) * NG) / TOT;
  if (a1 == a0) {
    int t = id - (int)a0;                      // 0..8191
    int bx = t & 15, by = (t >> 4) & 63, bz = t >> 10;
    transpose_body(w2, wt2, HID, DIM, bx, by, bz, (float(*)[65])smem);
    return;
  }
  int f = (int)a0;                             // gemm1 ordinal 0..2303
  typedef ushort_t (*lds4_t)[128][32];
  lds4_t A  = (lds4_t)smem;                    // 32 KiB
  lds4_t Bv = (lds4_t)(smem + 32768);          // 32 KiB

  const int nwg = NG;
  int lg = (f & 7) * (nwg >> 3) + (f >> 3);    // XCD chunk swizzle (bijective)
  int m_idx = lg % TMX;                        // m-inner: chunk reuses B-panels
  int n_idx = lg / TMX;
  int e = blk_e[m_idx];
  if (e < 0) return;
  int m0 = blk_m0[m_idx];
  int count = cur[e];
  int n0 = n_idx << 7;

  int tid = threadIdx.x;
  int lane = tid & 63, wid = tid >> 6;

  int srow = lane >> 2;
  int sunit = ((lane & 3) ^ ((lane >> 3) & 3)) << 3;
  int pA0 = m0 + wid * 16 + srow;
  int pA1 = pA0 + 64;
  int tok0 = (pA0 < count) ? (assign[e * BT + pA0] >> 1) : 0;
  int tok1 = (pA1 < count) ? (assign[e * BT + pA1] >> 1) : 0;
  const ushort_t* gA0 = xbf + (size_t)tok0 * DIM + sunit;
  const ushort_t* gA1 = xbf + (size_t)tok1 * DIM + sunit;
  const ushort_t* gB0 = wt1 + ((size_t)e * HID + n0 + wid * 16 + srow) * DIM + sunit;
  const ushort_t* gB1 = gB0 + (size_t)64 * DIM;

  int wm = wid >> 1, wn = wid & 1;             // wave tile: 64(m) x 64(n)
  int lr = lane & 15, g = lane >> 4;
  int xsw = ((g ^ ((lr >> 1) & 3)) << 3);
  f32x4 acc[4][4];
  f32x4 zero = {0.f, 0.f, 0.f, 0.f};
#pragma unroll
  for (int m = 0; m < 4; m++)
#pragma unroll
    for (int n = 0; n < 4; n++) acc[m][n] = zero;

#define STAGE(SL, K0)                                          \
  { GLOAD_LDS16(gA0 + (K0), &A[SL][wid * 16][0]);              \
    GLOAD_LDS16(gA1 + (K0), &A[SL][64 + wid * 16][0]);         \
    GLOAD_LDS16(gB0 + (K0), &Bv[SL][wid * 16][0]);             \
    GLOAD_LDS16(gB1 + (K0), &Bv[SL][64 + wid * 16][0]); }

  STAGE(0, 0);
  STAGE(1, 32);
  STAGE(2, 64);
  VM8;
  __builtin_amdgcn_s_barrier();
  __builtin_amdgcn_sched_barrier(0);

  const int NT = DIM / 32;                     // 32
  for (int t = 0; t < NT - 4; t += 4) {
    TILEK(0, t + 0, VM8, 1);
    TILEK(1, t + 1, VM8, 1);
    TILEK(2, t + 2, VM8, 1);
    TILEK(3, t + 3, VM8, 1);
  }
  TILEK(0, NT - 4, VM8, 1);
  TILEK(1, NT - 3, VM4, 0);
  TILEK(2, NT - 2, VM0, 0);
  TILEK(3, NT - 1, VMN, 0);
#undef STAGE

  int so = segoff[e];
#pragma unroll
  for (int m = 0; m < 4; m++) {
#pragma unroll
    for (int j = 0; j < 4; j++) {
      int p = m0 + wm * 64 + m * 16 + g * 4 + j;
      if (p >= count) continue;
      ushort_t* hr = hbuf + (size_t)(so + p) * HID;
#pragma unroll
      for (int n = 0; n < 4; n++) {
        int col = n0 + wn * 64 + n * 16 + lr;
        float v = acc[m][n][j] + b1[e * HID + col];
        float gl = 0.5f * v * (1.0f + erff(v * 0.70710678118654752f));
        hr[col] = f2bf(gl);
      }
    }
  }
}

// ============================================================================
// GEMM2 (R7, verified): contrib[slot][t] = h @ w2^T + b2.
// Grid 8n x TMX(72)m = 576, 2 blocks/CU.
// ============================================================================
__global__ __launch_bounds__(256, 2) void k_gemm2(
    const ushort_t* __restrict__ hbuf, const ushort_t* __restrict__ wt2,
    const float* __restrict__ b2,
    const int* __restrict__ assign, const int* __restrict__ cur,
    const int* __restrict__ segoff, const int* __restrict__ blk_e,
    const int* __restrict__ blk_m0, float* __restrict__ contrib) {
  const int nwg = 8 * TMX;                     // 576
  int f = blockIdx.x;
  int lg = (f & 7) * (nwg >> 3) + (f >> 3);
  int m_idx = lg % TMX;
  int n_idx = lg / TMX;
  int e = blk_e[m_idx];
  if (e < 0) return;
  int m0 = blk_m0[m_idx];
  int count = cur[e];
  int n0 = n_idx << 7;
  int so = segoff[e];

  __shared__ __attribute__((aligned(16))) ushort_t A[4][128][32];
  __shared__ __attribute__((aligned(16))) ushort_t Bv[4][128][32];
  int tid = threadIdx.x;
  int lane = tid & 63, wid = tid >> 6;

  int srow = lane >> 2;
  int sunit = ((lane & 3) ^ ((lane >> 3) & 3)) << 3;
  int pA0 = m0 + wid * 16 + srow;
  int pA1 = pA0 + 64;
  int pa0 = (pA0 < count) ? pA0 : (count - 1);
  int pa1 = (pA1 < count) ? pA1 : (count - 1);
  const ushort_t* gA0 = hbuf + (size_t)(so + pa0) * HID + sunit;
  const ushort_t* gA1 = hbuf + (size_t)(so + pa1) * HID + sunit;
  const ushort_t* gB0 = wt2 + ((size_t)e * DIM + n0 + wid * 16 + srow) * HID + sunit;
  const ushort_t* gB1 = gB0 + (size_t)64 * HID;

  int wm = wid >> 1, wn = wid & 1;
  int lr = lane & 15, g = lane >> 4;
  int xsw = ((g ^ ((lr >> 1) & 3)) << 3);
  f32x4 acc[4][4];
  f32x4 zero = {0.f, 0.f, 0.f, 0.f};
#pragma unroll
  for (int m = 0; m < 4; m++)
#pragma unroll
    for (int n = 0; n < 4; n++) acc[m][n] = zero;

#define STAGE(SL, K0)                                          \
  { GLOAD_LDS16(gA0 + (K0), &A[SL][wid * 16][0]);              \
    GLOAD_LDS16(gA1 + (K0), &A[SL][64 + wid * 16][0]);         \
    GLOAD_LDS16(gB0 + (K0), &Bv[SL][wid * 16][0]);             \
    GLOAD_LDS16(gB1 + (K0), &Bv[SL][64 + wid * 16][0]); }

  STAGE(0, 0);
  STAGE(1, 32);
  STAGE(2, 64);
  VM8;
  __builtin_amdgcn_s_barrier();
  __builtin_amdgcn_sched_barrier(0);

  const int NT = HID / 32;                     // 128
  for (int t = 0; t < NT - 4; t += 4) {
    TILEK(0, t + 0, VM8, 1);
    TILEK(1, t + 1, VM8, 1);
    TILEK(2, t + 2, VM8, 1);
    TILEK(3, t + 3, VM8, 1);
  }
  TILEK(0, NT - 4, VM8, 1);
  TILEK(1, NT - 3, VM4, 0);
  TILEK(2, NT - 2, VM0, 0);
  TILEK(3, NT - 1, VMN, 0);
#undef STAGE

#pragma unroll
  for (int m = 0; m < 4; m++) {
#pragma unroll
    for (int j = 0; j < 4; j++) {
      int p = m0 + wm * 64 + m * 16 + g * 4 + j;
      if (p >= count) continue;
      int a = assign[e * BT + p];
      int t = a >> 1, slot = a & 1;
      float* cr = contrib + ((size_t)slot * BT + t) * DIM;
#pragma unroll
      for (int n = 0; n < 4; n++) {
        int col = n0 + wn * 64 + n * 16 + lr;
        cr[col] = acc[m][n][j] + b2[e * DIM + col];
      }
    }
  }
}

// -------- combine: final = c0*probs[:,0] + c1*probs[:,1] --------
__global__ void k_combine(const float* __restrict__ contrib,
                          const float* __restrict__ probs01,
                          float* __restrict__ out) {
  int idx = blockIdx.x * blockDim.x + threadIdx.x;
  const int n4 = BT * DIM / 4;
  if (idx >= n4) return;
  int t = idx >> 8;
  float wA = probs01[t * 2 + 0], wB = probs01[t * 2 + 1];
  float4 c0 = ((const float4*)contrib)[idx];
  float4 c1 = ((const float4*)(contrib + (size_t)BT * DIM))[idx];
  float4 o;
  o.x = c0.x * wA + c1.x * wB;
  o.y = c0.y * wA + c1.y * wB;
  o.z = c0.z * wA + c1.z * wB;
  o.w = c0.w * wA + c1.w * wB;
  ((float4*)out)[idx] = o;
}

extern "C" void kernel_launch(void* const* d_in, const int* in_sizes, int n_in,
                              void* d_out, int out_size, void* d_ws, size_t ws_size,
                              hipStream_t stream) {
  const float* x  = (const float*)d_in[0];
  const float* wg = (const float*)d_in[1];
  const float* w1 = (const float*)d_in[2];
  const float* b1 = (const float*)d_in[3];
  const float* w2 = (const float*)d_in[4];
  const float* b2 = (const float*)d_in[5];
  float* out = (float*)d_out;
  float* logits_out = out + (size_t)BT * DIM;

  char* ws = (char*)d_ws;
  size_t off = 0;
  auto alloc = [&](size_t bytes) -> void* {
    void* p = ws + off;
    off = (off + bytes + 255) & ~(size_t)255;
    return p;
  };
  ushort_t* xbf    = (ushort_t*)alloc((size_t)BT * DIM * 2);
  ushort_t* wt1    = (ushort_t*)alloc((size_t)NE * HID * DIM * 2);
  ushort_t* wt2    = (ushort_t*)alloc((size_t)NE * DIM * HID * 2);
  ushort_t* hbuf   = (ushort_t*)alloc((size_t)2 * BT * HID * 2);
  float*    contrib= (float*)alloc((size_t)2 * BT * DIM * 4);
  float*    probs01= (float*)alloc((size_t)BT * 2 * 4);
  int*      assign = (int*)alloc((size_t)NE * BT * 4);
  int*      cur    = (int*)alloc(64);
  int*      segoff = (int*)alloc(64);
  int*      blk_e  = (int*)alloc(TMX * 4);
  int*      blk_m0 = (int*)alloc(TMX * 4);
  if (off > ws_size) return;

  hipMemsetAsync(cur, 0, NE * sizeof(int), stream);
  hipLaunchKernelGGL(k_prep_w1t, dim3(3 * BT), dim3(256), 0, stream,
                     x, wg, xbf, logits_out, probs01, assign, cur, w1, wt1);
  hipLaunchKernelGGL(k_plan, dim3(1), dim3(64), 0, stream, cur, segoff,
                     blk_e, blk_m0);
  hipLaunchKernelGGL(k_gemm1_w2t, dim3(32 * TMX + 8192), dim3(256), 0, stream,
                     xbf, wt1, b1, assign, cur, segoff, blk_e, blk_m0, hbuf,
                     w2, wt2);
  hipLaunchKernelGGL(k_gemm2, dim3(8 * TMX), dim3(256), 0, stream,
                     hbuf, wt2, b2, assign, cur, segoff, blk_e, blk_m0, contrib);
  hipLaunchKernelGGL(k_combine, dim3((BT * DIM / 4 + 255) / 256), dim3(256), 0, stream,
                     contrib, probs01, out);
}

// Round 10
// 515.881 us; speedup vs baseline: 1.0113x; 1.0113x over previous
//
#include <hip/hip_runtime.h>
#include <hip/hip_bf16.h>
#include <math.h>
#include <stdint.h>

#define BT  4096
#define DIM 1024
#define HID 4096
#define NE  8
#define TMX 72   // max active 128-row m-blocks

typedef __attribute__((ext_vector_type(8))) short short8v;
typedef __attribute__((ext_vector_type(4))) float f32x4;
typedef unsigned short ushort_t;

typedef __attribute__((address_space(1))) const void gas_void;
typedef __attribute__((address_space(3))) void las_void;
#define GLOAD_LDS16(g, l) __builtin_amdgcn_global_load_lds((gas_void*)(g), (las_void*)(l), 16, 0, 0)

__device__ inline ushort_t f2bf(float f) {
  __hip_bfloat16 b = __float2bfloat16(f);
  union { __hip_bfloat16 h; ushort_t u; } cv;
  cv.h = b;
  return cv.u;
}

// -------- fused prep + router: one block per token --------
__global__ __launch_bounds__(256) void k_prep_router(
    const float* __restrict__ x, const float* __restrict__ wg,
    ushort_t* __restrict__ xbf, float* __restrict__ logits_out,
    float* __restrict__ probs01, int* __restrict__ assign,
    int* __restrict__ cur) {
  int t = blockIdx.x;
  int tid = threadIdx.x;
  const float* xr = x + (size_t)t * DIM;
  float4 v = ((const float4*)xr)[tid];
  ushort4 o;
  o.x = f2bf(v.x); o.y = f2bf(v.y); o.z = f2bf(v.z); o.w = f2bf(v.w);
  ((ushort4*)(xbf + (size_t)t * DIM))[tid] = o;

  float vv[4] = {v.x, v.y, v.z, v.w};
  float part[NE];
#pragma unroll
  for (int e = 0; e < NE; e++) part[e] = 0.f;
#pragma unroll
  for (int i = 0; i < 4; i++) {
    const float4* wr = (const float4*)(wg + (size_t)(tid * 4 + i) * NE);
    float4 a = wr[0], b = wr[1];
    part[0] += vv[i] * a.x; part[1] += vv[i] * a.y;
    part[2] += vv[i] * a.z; part[3] += vv[i] * a.w;
    part[4] += vv[i] * b.x; part[5] += vv[i] * b.y;
    part[6] += vv[i] * b.z; part[7] += vv[i] * b.w;
  }
#pragma unroll
  for (int e = 0; e < NE; e++)
    for (int off = 32; off > 0; off >>= 1)
      part[e] += __shfl_xor(part[e], off);

  __shared__ float red[4][NE];
  int lane = tid & 63, wv = tid >> 6;
  if (lane == 0) {
#pragma unroll
    for (int e = 0; e < NE; e++) red[wv][e] = part[e];
  }
  __syncthreads();
  if (tid == 0) {
    float s8[NE];
#pragma unroll
    for (int e = 0; e < NE; e++)
      s8[e] = red[0][e] + red[1][e] + red[2][e] + red[3][e];
    float m = s8[0];
    for (int e = 1; e < NE; e++) m = fmaxf(m, s8[e]);
    float p[NE], s = 0.f;
    for (int e = 0; e < NE; e++) { p[e] = expf(s8[e] - m); s += p[e]; }
    float inv = 1.f / s;
    for (int e = 0; e < NE; e++) p[e] *= inv;
    for (int e = 0; e < NE; e++) logits_out[(size_t)t * NE + e] = s8[e];
    probs01[t * 2 + 0] = p[0];
    probs01[t * 2 + 1] = p[1];
    int b0 = 0;
    for (int e = 1; e < NE; e++) if (p[e] > p[b0]) b0 = e;
    int b1 = (b0 == 0) ? 1 : 0;
    for (int e = 0; e < NE; e++) if (e != b0 && p[e] > p[b1]) b1 = e;
    int pos0 = atomicAdd(&cur[b0], 1);
    assign[b0 * BT + pos0] = t * 2 + 0;
    int pos1 = atomicAdd(&cur[b1], 1);
    assign[b1 * BT + pos1] = t * 2 + 1;
  }
}

// -------- transpose+convert: src fp32 [E][R][C] -> dst bf16 [E][C][R] --------
// Also zeros cur[] (runs before k_prep_router in stream order).
__global__ __launch_bounds__(256) void k_transpose(const float* __restrict__ src,
                                                   ushort_t* __restrict__ dst,
                                                   int R, int C,
                                                   int* __restrict__ cur) {
  if (cur && blockIdx.x == 0 && blockIdx.y == 0 && blockIdx.z == 0 &&
      threadIdx.x < NE)
    cur[threadIdx.x] = 0;
  __shared__ float tile[64][65];
  int e = blockIdx.z;
  const float* s = src + (size_t)e * R * C;
  ushort_t* d = dst + (size_t)e * R * C;
  int c0 = blockIdx.x * 64, r0 = blockIdx.y * 64;
  int t = threadIdx.x;
  int lr = t >> 4;
  int lc4 = (t & 15) * 4;
#pragma unroll
  for (int i = 0; i < 4; i++) {
    int r = lr + 16 * i;
    float4 v = *(const float4*)&s[(size_t)(r0 + r) * C + c0 + lc4];
    tile[r][lc4 + 0] = v.x; tile[r][lc4 + 1] = v.y;
    tile[r][lc4 + 2] = v.z; tile[r][lc4 + 3] = v.w;
  }
  __syncthreads();
  int c = t >> 3, r8 = (t & 7) * 8;
#pragma unroll
  for (int p = 0; p < 2; p++) {
    int cc = c + 32 * p;
    short8v ov;
#pragma unroll
    for (int i = 0; i < 8; i++) ov[i] = (short)f2bf(tile[r8 + i][cc]);
    *(short8v*)&d[(size_t)(c0 + cc) * R + r0 + r8] = ov;
  }
}

// -------- plan: prefix offsets + flattened active 128-row block list --------
__global__ void k_plan(const int* __restrict__ cur, int* __restrict__ segoff,
                       int* __restrict__ blk_e, int* __restrict__ blk_m0) {
  if (threadIdx.x == 0 && blockIdx.x == 0) {
    int s = 0;
    for (int e = 0; e < NE; e++) { segoff[e] = s; s += cur[e]; }
    int t = 0;
    for (int e = 0; e < NE; e++) {
      int mb = (cur[e] + 127) >> 7;
      for (int i = 0; i < mb; i++) { blk_e[t] = e; blk_m0[t] = i << 7; t++; }
    }
    for (; t < TMX; t++) { blk_e[t] = -1; blk_m0[t] = 0; }
  }
}

// ============================================================================
// GEMM core: 128x128 tile, BK=32, ring-4 LDS = 64 KiB, 2 blocks/CU,
// 4 waves (2Mx2N), wave tile 64x64, acc[4][4].
// NEW (R10): register double-buffer pipeline.  Per step t:
//   STAGE(t+3) -> vmcnt(8) -> barrier (publishes t+1) -> sched_barrier ->
//   ds_read tile t+1 into NEXT reg set (no wait) ->
//   setprio(1) -> 16 MFMA of tile t from CUR reg set -> setprio(0)
// The reads of t+1 and MFMAs of t are independent -> LDS and MFMA pipes
// overlap WITHIN each wave (the prior lockstep read->MFMA serialized them).
// The lgkm wait for CUR regs resolved a full tile earlier (free).
// vmcnt ledger (4 gloads/tile/wave): steady vmcnt(8); tail 8,4,0.
// Slot safety: STAGE(t+3) (issued pre-barrier(t)) overwrites slot (t-1)&3;
// its reads were issued in step t-2 (>=1 full step ~600cyc earlier, DS
// latency ~120cyc) and the gload LDS-write lands >=200cyc post-issue.
// READ(t+1) targets slot (t+1)&3, overwritten next by STAGE(t+5) in step
// t+2 -- >=1 MFMA cluster + glob latency of slack.  Same discipline as
// R4-R7 (4x harness-verified bit-identical).
// ============================================================================
#define VM8 asm volatile("s_waitcnt vmcnt(8)" ::: "memory")
#define VM4 asm volatile("s_waitcnt vmcnt(4)" ::: "memory")
#define VM0 asm volatile("s_waitcnt vmcnt(0)" ::: "memory")
#define VMN do {} while (0)

#define READF(AF, BV, SL)                                                       \
  { _Pragma("unroll")                                                           \
    for (int n = 0; n < 4; n++)                                                 \
      BV[n] = *(const short8v*)&Bv[SL][wn * 64 + n * 16 + lr][xsw];             \
    _Pragma("unroll")                                                           \
    for (int m = 0; m < 4; m++)                                                 \
      AF[m] = *(const short8v*)&A[SL][wm * 64 + m * 16 + lr][xsw]; }

#define MFMA16(AF, BV)                                                          \
  { _Pragma("unroll")                                                           \
    for (int m = 0; m < 4; m++)                                                 \
      _Pragma("unroll")                                                         \
      for (int n = 0; n < 4; n++)                                               \
        acc[m][n] = __builtin_amdgcn_mfma_f32_16x16x32_bf16(AF[m], BV[n],       \
                                                            acc[m][n], 0, 0, 0); }

#define TSTEP(T, CA, CB, NA, NB, VMX, DOSTG)                                    \
  { if (DOSTG) { STAGE((((T) + 3) & 3), ((T) + 3) * 32); }                      \
    VMX;                                                                        \
    __builtin_amdgcn_s_barrier();                                               \
    __builtin_amdgcn_sched_barrier(0);                                          \
    READF(NA, NB, (((T) + 1) & 3));                                             \
    __builtin_amdgcn_s_setprio(1);                                              \
    MFMA16(CA, CB);                                                             \
    __builtin_amdgcn_s_setprio(0); }

// ============================================================================
// GEMM1: h = gelu(x_gathered @ w1^T + b1).  Grid 32n x TMX(72)m = 2304.
// ============================================================================
__global__ __launch_bounds__(256, 2) void k_gemm1(
    const ushort_t* __restrict__ xbf, const ushort_t* __restrict__ wt1,
    const float* __restrict__ b1,
    const int* __restrict__ assign, const int* __restrict__ cur,
    const int* __restrict__ segoff, const int* __restrict__ blk_e,
    const int* __restrict__ blk_m0, ushort_t* __restrict__ hbuf) {
  const int nwg = 32 * TMX;                    // 2304, divisible by 8
  int f = blockIdx.x;
  int lg = (f & 7) * (nwg >> 3) + (f >> 3);    // XCD chunk swizzle (bijective)
  int m_idx = lg % TMX;                        // m-inner: chunk reuses B-panels
  int n_idx = lg / TMX;
  int e = blk_e[m_idx];
  if (e < 0) return;
  int m0 = blk_m0[m_idx];
  int count = cur[e];
  int n0 = n_idx << 7;

  __shared__ __attribute__((aligned(16))) ushort_t A[4][128][32];
  __shared__ __attribute__((aligned(16))) ushort_t Bv[4][128][32];
  int tid = threadIdx.x;
  int lane = tid & 63, wid = tid >> 6;

  int srow = lane >> 2;
  int sunit = ((lane & 3) ^ ((lane >> 3) & 3)) << 3;
  int pA0 = m0 + wid * 16 + srow;
  int pA1 = pA0 + 64;
  int tok0 = (pA0 < count) ? (assign[e * BT + pA0] >> 1) : 0;
  int tok1 = (pA1 < count) ? (assign[e * BT + pA1] >> 1) : 0;
  const ushort_t* gA0 = xbf + (size_t)tok0 * DIM + sunit;
  const ushort_t* gA1 = xbf + (size_t)tok1 * DIM + sunit;
  const ushort_t* gB0 = wt1 + ((size_t)e * HID + n0 + wid * 16 + srow) * DIM + sunit;
  const ushort_t* gB1 = gB0 + (size_t)64 * DIM;

  int wm = wid >> 1, wn = wid & 1;             // wave tile: 64(m) x 64(n)
  int lr = lane & 15, g = lane >> 4;
  int xsw = ((g ^ ((lr >> 1) & 3)) << 3);
  f32x4 acc[4][4];
  f32x4 zero = {0.f, 0.f, 0.f, 0.f};
#pragma unroll
  for (int m = 0; m < 4; m++)
#pragma unroll
    for (int n = 0; n < 4; n++) acc[m][n] = zero;

#define STAGE(SL, K0)                                          \
  { GLOAD_LDS16(gA0 + (K0), &A[SL][wid * 16][0]);              \
    GLOAD_LDS16(gA1 + (K0), &A[SL][64 + wid * 16][0]);         \
    GLOAD_LDS16(gB0 + (K0), &Bv[SL][wid * 16][0]);             \
    GLOAD_LDS16(gB1 + (K0), &Bv[SL][64 + wid * 16][0]); }

  short8v afA[4], bvA[4], afB[4], bvB[4];
  STAGE(0, 0);
  STAGE(1, 32);
  STAGE(2, 64);
  VM8;
  __builtin_amdgcn_s_barrier();
  __builtin_amdgcn_sched_barrier(0);
  READF(afA, bvA, 0);

  const int NT = DIM / 32;                     // 32
  for (int t = 0; t < NT - 4; t += 2) {
    TSTEP(t,     afA, bvA, afB, bvB, VM8, 1);
    TSTEP(t + 1, afB, bvB, afA, bvA, VM8, 1);
  }
  TSTEP(NT - 4, afA, bvA, afB, bvB, VM8, 1);
  TSTEP(NT - 3, afB, bvB, afA, bvA, VM4, 0);
  TSTEP(NT - 2, afA, bvA, afB, bvB, VM0, 0);
  __builtin_amdgcn_s_setprio(1);
  MFMA16(afB, bvB);
  __builtin_amdgcn_s_setprio(0);
#undef STAGE

  int so = segoff[e];
#pragma unroll
  for (int m = 0; m < 4; m++) {
#pragma unroll
    for (int j = 0; j < 4; j++) {
      int p = m0 + wm * 64 + m * 16 + g * 4 + j;
      if (p >= count) continue;
      ushort_t* hr = hbuf + (size_t)(so + p) * HID;
#pragma unroll
      for (int n = 0; n < 4; n++) {
        int col = n0 + wn * 64 + n * 16 + lr;
        float v = acc[m][n][j] + b1[e * HID + col];
        float gl = 0.5f * v * (1.0f + erff(v * 0.70710678118654752f));
        hr[col] = f2bf(gl);
      }
    }
  }
}

// ============================================================================
// GEMM2: contrib[slot][t] = h @ w2^T + b2.  Grid 8n x TMX(72)m = 576.
// ============================================================================
__global__ __launch_bounds__(256, 2) void k_gemm2(
    const ushort_t* __restrict__ hbuf, const ushort_t* __restrict__ wt2,
    const float* __restrict__ b2,
    const int* __restrict__ assign, const int* __restrict__ cur,
    const int* __restrict__ segoff, const int* __restrict__ blk_e,
    const int* __restrict__ blk_m0, float* __restrict__ contrib) {
  const int nwg = 8 * TMX;                     // 576, divisible by 8
  int f = blockIdx.x;
  int lg = (f & 7) * (nwg >> 3) + (f >> 3);
  int m_idx = lg % TMX;
  int n_idx = lg / TMX;
  int e = blk_e[m_idx];
  if (e < 0) return;
  int m0 = blk_m0[m_idx];
  int count = cur[e];
  int n0 = n_idx << 7;
  int so = segoff[e];

  __shared__ __attribute__((aligned(16))) ushort_t A[4][128][32];
  __shared__ __attribute__((aligned(16))) ushort_t Bv[4][128][32];
  int tid = threadIdx.x;
  int lane = tid & 63, wid = tid >> 6;

  int srow = lane >> 2;
  int sunit = ((lane & 3) ^ ((lane >> 3) & 3)) << 3;
  int pA0 = m0 + wid * 16 + srow;
  int pA1 = pA0 + 64;
  int pa0 = (pA0 < count) ? pA0 : (count - 1);
  int pa1 = (pA1 < count) ? pA1 : (count - 1);
  const ushort_t* gA0 = hbuf + (size_t)(so + pa0) * HID + sunit;
  const ushort_t* gA1 = hbuf + (size_t)(so + pa1) * HID + sunit;
  const ushort_t* gB0 = wt2 + ((size_t)e * DIM + n0 + wid * 16 + srow) * HID + sunit;
  const ushort_t* gB1 = gB0 + (size_t)64 * HID;

  int wm = wid >> 1, wn = wid & 1;             // wave tile: 64(m) x 64(n)
  int lr = lane & 15, g = lane >> 4;
  int xsw = ((g ^ ((lr >> 1) & 3)) << 3);
  f32x4 acc[4][4];
  f32x4 zero = {0.f, 0.f, 0.f, 0.f};
#pragma unroll
  for (int m = 0; m < 4; m++)
#pragma unroll
    for (int n = 0; n < 4; n++) acc[m][n] = zero;

#define STAGE(SL, K0)                                          \
  { GLOAD_LDS16(gA0 + (K0), &A[SL][wid * 16][0]);              \
    GLOAD_LDS16(gA1 + (K0), &A[SL][64 + wid * 16][0]);         \
    GLOAD_LDS16(gB0 + (K0), &Bv[SL][wid * 16][0]);             \
    GLOAD_LDS16(gB1 + (K0), &Bv[SL][64 + wid * 16][0]); }

  short8v afA[4], bvA[4], afB[4], bvB[4];
  STAGE(0, 0);
  STAGE(1, 32);
  STAGE(2, 64);
  VM8;
  __builtin_amdgcn_s_barrier();
  __builtin_amdgcn_sched_barrier(0);
  READF(afA, bvA, 0);

  const int NT = HID / 32;                     // 128
  for (int t = 0; t < NT - 4; t += 2) {
    TSTEP(t,     afA, bvA, afB, bvB, VM8, 1);
    TSTEP(t + 1, afB, bvB, afA, bvA, VM8, 1);
  }
  TSTEP(NT - 4, afA, bvA, afB, bvB, VM8, 1);
  TSTEP(NT - 3, afB, bvB, afA, bvA, VM4, 0);
  TSTEP(NT - 2, afA, bvA, afB, bvB, VM0, 0);
  __builtin_amdgcn_s_setprio(1);
  MFMA16(afB, bvB);
  __builtin_amdgcn_s_setprio(0);
#undef STAGE

#pragma unroll
  for (int m = 0; m < 4; m++) {
#pragma unroll
    for (int j = 0; j < 4; j++) {
      int p = m0 + wm * 64 + m * 16 + g * 4 + j;
      if (p >= count) continue;
      int a = assign[e * BT + p];
      int t = a >> 1, slot = a & 1;
      float* cr = contrib + ((size_t)slot * BT + t) * DIM;
#pragma unroll
      for (int n = 0; n < 4; n++) {
        int col = n0 + wn * 64 + n * 16 + lr;
        cr[col] = acc[m][n][j] + b2[e * DIM + col];
      }
    }
  }
}

// -------- combine: final = c0*probs[:,0] + c1*probs[:,1] --------
__global__ void k_combine(const float* __restrict__ contrib,
                          const float* __restrict__ probs01,
                          float* __restrict__ out) {
  int idx = blockIdx.x * blockDim.x + threadIdx.x;
  const int n4 = BT * DIM / 4;
  if (idx >= n4) return;
  int t = idx >> 8;
  float wA = probs01[t * 2 + 0], wB = probs01[t * 2 + 1];
  float4 c0 = ((const float4*)contrib)[idx];
  float4 c1 = ((const float4*)(contrib + (size_t)BT * DIM))[idx];
  float4 o;
  o.x = c0.x * wA + c1.x * wB;
  o.y = c0.y * wA + c1.y * wB;
  o.z = c0.z * wA + c1.z * wB;
  o.w = c0.w * wA + c1.w * wB;
  ((float4*)out)[idx] = o;
}

extern "C" void kernel_launch(void* const* d_in, const int* in_sizes, int n_in,
                              void* d_out, int out_size, void* d_ws, size_t ws_size,
                              hipStream_t stream) {
  const float* x  = (const float*)d_in[0];
  const float* wg = (const float*)d_in[1];
  const float* w1 = (const float*)d_in[2];
  const float* b1 = (const float*)d_in[3];
  const float* w2 = (const float*)d_in[4];
  const float* b2 = (const float*)d_in[5];
  float* out = (float*)d_out;
  float* logits_out = out + (size_t)BT * DIM;

  char* ws = (char*)d_ws;
  size_t off = 0;
  auto alloc = [&](size_t bytes) -> void* {
    void* p = ws + off;
    off = (off + bytes + 255) & ~(size_t)255;
    return p;
  };
  ushort_t* xbf    = (ushort_t*)alloc((size_t)BT * DIM * 2);
  ushort_t* wt1    = (ushort_t*)alloc((size_t)NE * HID * DIM * 2);
  ushort_t* wt2    = (ushort_t*)alloc((size_t)NE * DIM * HID * 2);
  ushort_t* hbuf   = (ushort_t*)alloc((size_t)2 * BT * HID * 2);
  float*    contrib= (float*)alloc((size_t)2 * BT * DIM * 4);
  float*    probs01= (float*)alloc((size_t)BT * 2 * 4);
  int*      assign = (int*)alloc((size_t)NE * BT * 4);
  int*      cur    = (int*)alloc(64);
  int*      segoff = (int*)alloc(64);
  int*      blk_e  = (int*)alloc(TMX * 4);
  int*      blk_m0 = (int*)alloc(TMX * 4);
  if (off > ws_size) return;

  // transpose(w1) also zeros cur; stream order puts it before k_prep_router.
  hipLaunchKernelGGL(k_transpose, dim3(HID / 64, DIM / 64, NE), dim3(256), 0, stream,
                     w1, wt1, DIM, HID, cur);
  hipLaunchKernelGGL(k_transpose, dim3(DIM / 64, HID / 64, NE), dim3(256), 0, stream,
                     w2, wt2, HID, DIM, (int*)nullptr);
  hipLaunchKernelGGL(k_prep_router, dim3(BT), dim3(256), 0, stream,
                     x, wg, xbf, logits_out, probs01, assign, cur);
  hipLaunchKernelGGL(k_plan, dim3(1), dim3(64), 0, stream, cur, segoff,
                     blk_e, blk_m0);
  hipLaunchKernelGGL(k_gemm1, dim3(32 * TMX), dim3(256), 0, stream,
                     xbf, wt1, b1, assign, cur, segoff, blk_e, blk_m0, hbuf);
  hipLaunchKernelGGL(k_gemm2, dim3(8 * TMX), dim3(256), 0, stream,
                     hbuf, wt2, b2, assign, cur, segoff, blk_e, blk_m0, contrib);
  hipLaunchKernelGGL(k_combine, dim3((BT * DIM / 4 + 255) / 256), dim3(256), 0, stream,
                     contrib, probs01, out);
}

// Round 11
// 456.703 us; speedup vs baseline: 1.1423x; 1.1296x over previous
//
#include <hip/hip_runtime.h>
#include <hip/hip_bf16.h>
#include <math.h>
#include <stdint.h>

#define BT  4096
#define DIM 1024
#define HID 4096
#define NE  8
#define TMX 72   // max active 128-row m-blocks

typedef __attribute__((ext_vector_type(8))) short short8v;
typedef __attribute__((ext_vector_type(4))) float f32x4;
typedef unsigned short ushort_t;

typedef __attribute__((address_space(1))) const void gas_void;
typedef __attribute__((address_space(3))) void las_void;
#define GLOAD_LDS16(g, l) __builtin_amdgcn_global_load_lds((gas_void*)(g), (las_void*)(l), 16, 0, 0)

__device__ inline ushort_t f2bf(float f) {
  __hip_bfloat16 b = __float2bfloat16(f);
  union { __hip_bfloat16 h; ushort_t u; } cv;
  cv.h = b;
  return cv.u;
}

// -------- fused prep + router: one block per token --------
__global__ __launch_bounds__(256) void k_prep_router(
    const float* __restrict__ x, const float* __restrict__ wg,
    ushort_t* __restrict__ xbf, float* __restrict__ logits_out,
    float* __restrict__ probs01, int* __restrict__ assign,
    int* __restrict__ cur) {
  int t = blockIdx.x;
  int tid = threadIdx.x;
  const float* xr = x + (size_t)t * DIM;
  float4 v = ((const float4*)xr)[tid];
  ushort4 o;
  o.x = f2bf(v.x); o.y = f2bf(v.y); o.z = f2bf(v.z); o.w = f2bf(v.w);
  ((ushort4*)(xbf + (size_t)t * DIM))[tid] = o;

  float vv[4] = {v.x, v.y, v.z, v.w};
  float part[NE];
#pragma unroll
  for (int e = 0; e < NE; e++) part[e] = 0.f;
#pragma unroll
  for (int i = 0; i < 4; i++) {
    const float4* wr = (const float4*)(wg + (size_t)(tid * 4 + i) * NE);
    float4 a = wr[0], b = wr[1];
    part[0] += vv[i] * a.x; part[1] += vv[i] * a.y;
    part[2] += vv[i] * a.z; part[3] += vv[i] * a.w;
    part[4] += vv[i] * b.x; part[5] += vv[i] * b.y;
    part[6] += vv[i] * b.z; part[7] += vv[i] * b.w;
  }
#pragma unroll
  for (int e = 0; e < NE; e++)
    for (int off = 32; off > 0; off >>= 1)
      part[e] += __shfl_xor(part[e], off);

  __shared__ float red[4][NE];
  int lane = tid & 63, wv = tid >> 6;
  if (lane == 0) {
#pragma unroll
    for (int e = 0; e < NE; e++) red[wv][e] = part[e];
  }
  __syncthreads();
  if (tid == 0) {
    float s8[NE];
#pragma unroll
    for (int e = 0; e < NE; e++)
      s8[e] = red[0][e] + red[1][e] + red[2][e] + red[3][e];
    float m = s8[0];
    for (int e = 1; e < NE; e++) m = fmaxf(m, s8[e]);
    float p[NE], s = 0.f;
    for (int e = 0; e < NE; e++) { p[e] = expf(s8[e] - m); s += p[e]; }
    float inv = 1.f / s;
    for (int e = 0; e < NE; e++) p[e] *= inv;
    for (int e = 0; e < NE; e++) logits_out[(size_t)t * NE + e] = s8[e];
    probs01[t * 2 + 0] = p[0];
    probs01[t * 2 + 1] = p[1];
    int b0 = 0;
    for (int e = 1; e < NE; e++) if (p[e] > p[b0]) b0 = e;
    int b1 = (b0 == 0) ? 1 : 0;
    for (int e = 0; e < NE; e++) if (e != b0 && p[e] > p[b1]) b1 = e;
    int pos0 = atomicAdd(&cur[b0], 1);
    assign[b0 * BT + pos0] = t * 2 + 0;
    int pos1 = atomicAdd(&cur[b1], 1);
    assign[b1 * BT + pos1] = t * 2 + 1;
  }
}

// -------- transpose+convert: src fp32 [E][R][C] -> dst bf16 [E][C][R] --------
// Also zeros cur[] (runs before k_prep_router in stream order).
__global__ __launch_bounds__(256) void k_transpose(const float* __restrict__ src,
                                                   ushort_t* __restrict__ dst,
                                                   int R, int C,
                                                   int* __restrict__ cur) {
  if (cur && blockIdx.x == 0 && blockIdx.y == 0 && blockIdx.z == 0 &&
      threadIdx.x < NE)
    cur[threadIdx.x] = 0;
  __shared__ float tile[64][65];
  int e = blockIdx.z;
  const float* s = src + (size_t)e * R * C;
  ushort_t* d = dst + (size_t)e * R * C;
  int c0 = blockIdx.x * 64, r0 = blockIdx.y * 64;
  int t = threadIdx.x;
  int lr = t >> 4;
  int lc4 = (t & 15) * 4;
#pragma unroll
  for (int i = 0; i < 4; i++) {
    int r = lr + 16 * i;
    float4 v = *(const float4*)&s[(size_t)(r0 + r) * C + c0 + lc4];
    tile[r][lc4 + 0] = v.x; tile[r][lc4 + 1] = v.y;
    tile[r][lc4 + 2] = v.z; tile[r][lc4 + 3] = v.w;
  }
  __syncthreads();
  int c = t >> 3, r8 = (t & 7) * 8;
#pragma unroll
  for (int p = 0; p < 2; p++) {
    int cc = c + 32 * p;
    short8v ov;
#pragma unroll
    for (int i = 0; i < 8; i++) ov[i] = (short)f2bf(tile[r8 + i][cc]);
    *(short8v*)&d[(size_t)(c0 + cc) * R + r0 + r8] = ov;
  }
}

// -------- plan: prefix offsets + flattened active 128-row block list --------
__global__ void k_plan(const int* __restrict__ cur, int* __restrict__ segoff,
                       int* __restrict__ blk_e, int* __restrict__ blk_m0) {
  if (threadIdx.x == 0 && blockIdx.x == 0) {
    int s = 0;
    for (int e = 0; e < NE; e++) { segoff[e] = s; s += cur[e]; }
    int t = 0;
    for (int e = 0; e < NE; e++) {
      int mb = (cur[e] + 127) >> 7;
      for (int i = 0; i < mb; i++) { blk_e[t] = e; blk_m0[t] = i << 7; t++; }
    }
    for (; t < TMX; t++) { blk_e[t] = -1; blk_m0[t] = 0; }
  }
}

// ============================================================================
// GEMM core (R11): 128x128 tile, BK=32, ring-4 LDS = 64 KiB, 2 blocks/CU,
// NOW 512 thr = 8 waves (2M x 4N), wave tile 64x32, acc[4][2].
// -> 16 waves/CU = 4 waves/SIMD (double every prior variant): when a wave
// stalls at vmcnt/barrier, its SIMD has 3 other candidates (m114 TLP).
// Inner-loop discipline identical to R7 (4x harness-verified): per K-tile
//   reads(t) -> STAGE(t+3): 2 gloads -> vmcnt(4) -> barrier(publishes t+1)
//   -> sched_barrier -> setprio -> 8 MFMA -> setprio
// Staging: ONE gload per operand per tile (512thr x 16B = 128rows x 32cols);
// wave w stages rows w*16..w*16+15 (wave-uniform base + lane*16).
// vmcnt ledger (2 loads/tile/thread): steady vmcnt(4); tail 2,0.
// Swizzle identical (64B rows): store unit u^((row>>1)&3); stage source
// sunit=(l&3)^((l>>3)&3); read xsw=(g^((lr>>1)&3)).
// ============================================================================
#define VM4 asm volatile("s_waitcnt vmcnt(4)" ::: "memory")
#define VM2 asm volatile("s_waitcnt vmcnt(2)" ::: "memory")
#define VM0 asm volatile("s_waitcnt vmcnt(0)" ::: "memory")
#define VMN do {} while (0)

#define TILEK(TB, T, VMX, DOSTG)                                                \
  { short8v bv[2], af[4];                                                       \
    _Pragma("unroll")                                                           \
    for (int n = 0; n < 2; n++)                                                 \
      bv[n] = *(const short8v*)&Bv[TB][wn * 32 + n * 16 + lr][xsw];             \
    _Pragma("unroll")                                                           \
    for (int m = 0; m < 4; m++)                                                 \
      af[m] = *(const short8v*)&A[TB][wm * 64 + m * 16 + lr][xsw];              \
    if (DOSTG) { STAGE((((TB) + 3) & 3), ((T) + 3) * 32); }                     \
    VMX;                                                                        \
    __builtin_amdgcn_s_barrier();                                               \
    __builtin_amdgcn_sched_barrier(0);                                          \
    __builtin_amdgcn_s_setprio(1);                                              \
    _Pragma("unroll")                                                           \
    for (int m = 0; m < 4; m++)                                                 \
      _Pragma("unroll")                                                         \
      for (int n = 0; n < 2; n++)                                               \
        acc[m][n] = __builtin_amdgcn_mfma_f32_16x16x32_bf16(af[m], bv[n],       \
                                                            acc[m][n], 0, 0, 0);\
    __builtin_amdgcn_s_setprio(0); }

// ============================================================================
// GEMM1: h = gelu(x_gathered @ w1^T + b1).  Grid 32n x TMX(72)m = 2304.
// ============================================================================
__global__ __launch_bounds__(512, 4) void k_gemm1(
    const ushort_t* __restrict__ xbf, const ushort_t* __restrict__ wt1,
    const float* __restrict__ b1,
    const int* __restrict__ assign, const int* __restrict__ cur,
    const int* __restrict__ segoff, const int* __restrict__ blk_e,
    const int* __restrict__ blk_m0, ushort_t* __restrict__ hbuf) {
  const int nwg = 32 * TMX;                    // 2304, divisible by 8
  int f = blockIdx.x;
  int lg = (f & 7) * (nwg >> 3) + (f >> 3);    // XCD chunk swizzle (bijective)
  int m_idx = lg % TMX;                        // m-inner: chunk reuses B-panels
  int n_idx = lg / TMX;
  int e = blk_e[m_idx];
  if (e < 0) return;
  int m0 = blk_m0[m_idx];
  int count = cur[e];
  int n0 = n_idx << 7;

  __shared__ __attribute__((aligned(16))) ushort_t A[4][128][32];
  __shared__ __attribute__((aligned(16))) ushort_t Bv[4][128][32];
  int tid = threadIdx.x;
  int lane = tid & 63, wid = tid >> 6;

  int srow = lane >> 2;                        // 0..15 within wave's 16 rows
  int sunit = ((lane & 3) ^ ((lane >> 3) & 3)) << 3;
  int pA0 = m0 + wid * 16 + srow;
  int tok0 = (pA0 < count) ? (assign[e * BT + pA0] >> 1) : 0;
  const ushort_t* gA0 = xbf + (size_t)tok0 * DIM + sunit;
  const ushort_t* gB0 = wt1 + ((size_t)e * HID + n0 + wid * 16 + srow) * DIM + sunit;

  int wm = wid >> 2, wn = wid & 3;             // wave tile: 64(m) x 32(n)
  int lr = lane & 15, g = lane >> 4;
  int xsw = ((g ^ ((lr >> 1) & 3)) << 3);
  f32x4 acc[4][2];
  f32x4 zero = {0.f, 0.f, 0.f, 0.f};
#pragma unroll
  for (int m = 0; m < 4; m++)
#pragma unroll
    for (int n = 0; n < 2; n++) acc[m][n] = zero;

#define STAGE(SL, K0)                                          \
  { GLOAD_LDS16(gA0 + (K0), &A[SL][wid * 16][0]);              \
    GLOAD_LDS16(gB0 + (K0), &Bv[SL][wid * 16][0]); }

  STAGE(0, 0);
  STAGE(1, 32);
  STAGE(2, 64);
  VM4;
  __builtin_amdgcn_s_barrier();
  __builtin_amdgcn_sched_barrier(0);

  const int NT = DIM / 32;                     // 32
  for (int t = 0; t < NT - 4; t += 4) {
    TILEK(0, t + 0, VM4, 1);
    TILEK(1, t + 1, VM4, 1);
    TILEK(2, t + 2, VM4, 1);
    TILEK(3, t + 3, VM4, 1);
  }
  TILEK(0, NT - 4, VM4, 1);
  TILEK(1, NT - 3, VM2, 0);
  TILEK(2, NT - 2, VM0, 0);
  TILEK(3, NT - 1, VMN, 0);
#undef STAGE

  int so = segoff[e];
#pragma unroll
  for (int m = 0; m < 4; m++) {
#pragma unroll
    for (int j = 0; j < 4; j++) {
      int p = m0 + wm * 64 + m * 16 + g * 4 + j;
      if (p >= count) continue;
      ushort_t* hr = hbuf + (size_t)(so + p) * HID;
#pragma unroll
      for (int n = 0; n < 2; n++) {
        int col = n0 + wn * 32 + n * 16 + lr;
        float v = acc[m][n][j] + b1[e * HID + col];
        float gl = 0.5f * v * (1.0f + erff(v * 0.70710678118654752f));
        hr[col] = f2bf(gl);
      }
    }
  }
}

// ============================================================================
// GEMM2: contrib[slot][t] = h @ w2^T + b2.  Grid 8n x TMX(72)m = 576.
// ============================================================================
__global__ __launch_bounds__(512, 4) void k_gemm2(
    const ushort_t* __restrict__ hbuf, const ushort_t* __restrict__ wt2,
    const float* __restrict__ b2,
    const int* __restrict__ assign, const int* __restrict__ cur,
    const int* __restrict__ segoff, const int* __restrict__ blk_e,
    const int* __restrict__ blk_m0, float* __restrict__ contrib) {
  const int nwg = 8 * TMX;                     // 576, divisible by 8
  int f = blockIdx.x;
  int lg = (f & 7) * (nwg >> 3) + (f >> 3);
  int m_idx = lg % TMX;
  int n_idx = lg / TMX;
  int e = blk_e[m_idx];
  if (e < 0) return;
  int m0 = blk_m0[m_idx];
  int count = cur[e];
  int n0 = n_idx << 7;
  int so = segoff[e];

  __shared__ __attribute__((aligned(16))) ushort_t A[4][128][32];
  __shared__ __attribute__((aligned(16))) ushort_t Bv[4][128][32];
  int tid = threadIdx.x;
  int lane = tid & 63, wid = tid >> 6;

  int srow = lane >> 2;
  int sunit = ((lane & 3) ^ ((lane >> 3) & 3)) << 3;
  int pA0 = m0 + wid * 16 + srow;
  int pa0 = (pA0 < count) ? pA0 : (count - 1);
  const ushort_t* gA0 = hbuf + (size_t)(so + pa0) * HID + sunit;
  const ushort_t* gB0 = wt2 + ((size_t)e * DIM + n0 + wid * 16 + srow) * HID + sunit;

  int wm = wid >> 2, wn = wid & 3;             // wave tile: 64(m) x 32(n)
  int lr = lane & 15, g = lane >> 4;
  int xsw = ((g ^ ((lr >> 1) & 3)) << 3);
  f32x4 acc[4][2];
  f32x4 zero = {0.f, 0.f, 0.f, 0.f};
#pragma unroll
  for (int m = 0; m < 4; m++)
#pragma unroll
    for (int n = 0; n < 2; n++) acc[m][n] = zero;

#define STAGE(SL, K0)                                          \
  { GLOAD_LDS16(gA0 + (K0), &A[SL][wid * 16][0]);              \
    GLOAD_LDS16(gB0 + (K0), &Bv[SL][wid * 16][0]); }

  STAGE(0, 0);
  STAGE(1, 32);
  STAGE(2, 64);
  VM4;
  __builtin_amdgcn_s_barrier();
  __builtin_amdgcn_sched_barrier(0);

  const int NT = HID / 32;                     // 128
  for (int t = 0; t < NT - 4; t += 4) {
    TILEK(0, t + 0, VM4, 1);
    TILEK(1, t + 1, VM4, 1);
    TILEK(2, t + 2, VM4, 1);
    TILEK(3, t + 3, VM4, 1);
  }
  TILEK(0, NT - 4, VM4, 1);
  TILEK(1, NT - 3, VM2, 0);
  TILEK(2, NT - 2, VM0, 0);
  TILEK(3, NT - 1, VMN, 0);
#undef STAGE

#pragma unroll
  for (int m = 0; m < 4; m++) {
#pragma unroll
    for (int j = 0; j < 4; j++) {
      int p = m0 + wm * 64 + m * 16 + g * 4 + j;
      if (p >= count) continue;
      int a = assign[e * BT + p];
      int t = a >> 1, slot = a & 1;
      float* cr = contrib + ((size_t)slot * BT + t) * DIM;
#pragma unroll
      for (int n = 0; n < 2; n++) {
        int col = n0 + wn * 32 + n * 16 + lr;
        cr[col] = acc[m][n][j] + b2[e * DIM + col];
      }
    }
  }
}

// -------- combine: final = c0*probs[:,0] + c1*probs[:,1] --------
__global__ void k_combine(const float* __restrict__ contrib,
                          const float* __restrict__ probs01,
                          float* __restrict__ out) {
  int idx = blockIdx.x * blockDim.x + threadIdx.x;
  const int n4 = BT * DIM / 4;
  if (idx >= n4) return;
  int t = idx >> 8;
  float wA = probs01[t * 2 + 0], wB = probs01[t * 2 + 1];
  float4 c0 = ((const float4*)contrib)[idx];
  float4 c1 = ((const float4*)(contrib + (size_t)BT * DIM))[idx];
  float4 o;
  o.x = c0.x * wA + c1.x * wB;
  o.y = c0.y * wA + c1.y * wB;
  o.z = c0.z * wA + c1.z * wB;
  o.w = c0.w * wA + c1.w * wB;
  ((float4*)out)[idx] = o;
}

extern "C" void kernel_launch(void* const* d_in, const int* in_sizes, int n_in,
                              void* d_out, int out_size, void* d_ws, size_t ws_size,
                              hipStream_t stream) {
  const float* x  = (const float*)d_in[0];
  const float* wg = (const float*)d_in[1];
  const float* w1 = (const float*)d_in[2];
  const float* b1 = (const float*)d_in[3];
  const float* w2 = (const float*)d_in[4];
  const float* b2 = (const float*)d_in[5];
  float* out = (float*)d_out;
  float* logits_out = out + (size_t)BT * DIM;

  char* ws = (char*)d_ws;
  size_t off = 0;
  auto alloc = [&](size_t bytes) -> void* {
    void* p = ws + off;
    off = (off + bytes + 255) & ~(size_t)255;
    return p;
  };
  ushort_t* xbf    = (ushort_t*)alloc((size_t)BT * DIM * 2);
  ushort_t* wt1    = (ushort_t*)alloc((size_t)NE * HID * DIM * 2);
  ushort_t* wt2    = (ushort_t*)alloc((size_t)NE * DIM * HID * 2);
  ushort_t* hbuf   = (ushort_t*)alloc((size_t)2 * BT * HID * 2);
  float*    contrib= (float*)alloc((size_t)2 * BT * DIM * 4);
  float*    probs01= (float*)alloc((size_t)BT * 2 * 4);
  int*      assign = (int*)alloc((size_t)NE * BT * 4);
  int*      cur    = (int*)alloc(64);
  int*      segoff = (int*)alloc(64);
  int*      blk_e  = (int*)alloc(TMX * 4);
  int*      blk_m0 = (int*)alloc(TMX * 4);
  if (off > ws_size) return;

  // transpose(w1) also zeros cur; stream order puts it before k_prep_router.
  hipLaunchKernelGGL(k_transpose, dim3(HID / 64, DIM / 64, NE), dim3(256), 0, stream,
                     w1, wt1, DIM, HID, cur);
  hipLaunchKernelGGL(k_transpose, dim3(DIM / 64, HID / 64, NE), dim3(256), 0, stream,
                     w2, wt2, HID, DIM, (int*)nullptr);
  hipLaunchKernelGGL(k_prep_router, dim3(BT), dim3(256), 0, stream,
                     x, wg, xbf, logits_out, probs01, assign, cur);
  hipLaunchKernelGGL(k_plan, dim3(1), dim3(64), 0, stream, cur, segoff,
                     blk_e, blk_m0);
  hipLaunchKernelGGL(k_gemm1, dim3(32 * TMX), dim3(512), 0, stream,
                     xbf, wt1, b1, assign, cur, segoff, blk_e, blk_m0, hbuf);
  hipLaunchKernelGGL(k_gemm2, dim3(8 * TMX), dim3(512), 0, stream,
                     hbuf, wt2, b2, assign, cur, segoff, blk_e, blk_m0, contrib);
  hipLaunchKernelGGL(k_combine, dim3((BT * DIM / 4 + 255) / 256), dim3(256), 0, stream,
                     contrib, probs01, out);
}

// Round 12
// 441.137 us; speedup vs baseline: 1.1827x; 1.0353x over previous
//
#include <hip/hip_runtime.h>
#include <hip/hip_bf16.h>
#include <math.h>
#include <stdint.h>

#define BT  4096
#define DIM 1024
#define HID 4096
#define NE  8
#define TMX 72   // max active 128-row m-blocks

typedef __attribute__((ext_vector_type(8))) short short8v;
typedef __attribute__((ext_vector_type(4))) float f32x4;
typedef unsigned short ushort_t;

typedef __attribute__((address_space(1))) const void gas_void;
typedef __attribute__((address_space(3))) void las_void;
#define GLOAD_LDS16(g, l) __builtin_amdgcn_global_load_lds((gas_void*)(g), (las_void*)(l), 16, 0, 0)

__device__ inline ushort_t f2bf(float f) {
  __hip_bfloat16 b = __float2bfloat16(f);
  union { __hip_bfloat16 h; ushort_t u; } cv;
  cv.h = b;
  return cv.u;
}

// -------- fused prep + router: one block per token --------
__global__ __launch_bounds__(256) void k_prep_router(
    const float* __restrict__ x, const float* __restrict__ wg,
    ushort_t* __restrict__ xbf, float* __restrict__ logits_out,
    float* __restrict__ probs01, int* __restrict__ assign,
    int* __restrict__ cur) {
  int t = blockIdx.x;
  int tid = threadIdx.x;
  const float* xr = x + (size_t)t * DIM;
  float4 v = ((const float4*)xr)[tid];
  ushort4 o;
  o.x = f2bf(v.x); o.y = f2bf(v.y); o.z = f2bf(v.z); o.w = f2bf(v.w);
  ((ushort4*)(xbf + (size_t)t * DIM))[tid] = o;

  float vv[4] = {v.x, v.y, v.z, v.w};
  float part[NE];
#pragma unroll
  for (int e = 0; e < NE; e++) part[e] = 0.f;
#pragma unroll
  for (int i = 0; i < 4; i++) {
    const float4* wr = (const float4*)(wg + (size_t)(tid * 4 + i) * NE);
    float4 a = wr[0], b = wr[1];
    part[0] += vv[i] * a.x; part[1] += vv[i] * a.y;
    part[2] += vv[i] * a.z; part[3] += vv[i] * a.w;
    part[4] += vv[i] * b.x; part[5] += vv[i] * b.y;
    part[6] += vv[i] * b.z; part[7] += vv[i] * b.w;
  }
#pragma unroll
  for (int e = 0; e < NE; e++)
    for (int off = 32; off > 0; off >>= 1)
      part[e] += __shfl_xor(part[e], off);

  __shared__ float red[4][NE];
  int lane = tid & 63, wv = tid >> 6;
  if (lane == 0) {
#pragma unroll
    for (int e = 0; e < NE; e++) red[wv][e] = part[e];
  }
  __syncthreads();
  if (tid == 0) {
    float s8[NE];
#pragma unroll
    for (int e = 0; e < NE; e++)
      s8[e] = red[0][e] + red[1][e] + red[2][e] + red[3][e];
    float m = s8[0];
    for (int e = 1; e < NE; e++) m = fmaxf(m, s8[e]);
    float p[NE], s = 0.f;
    for (int e = 0; e < NE; e++) { p[e] = expf(s8[e] - m); s += p[e]; }
    float inv = 1.f / s;
    for (int e = 0; e < NE; e++) p[e] *= inv;
    for (int e = 0; e < NE; e++) logits_out[(size_t)t * NE + e] = s8[e];
    probs01[t * 2 + 0] = p[0];
    probs01[t * 2 + 1] = p[1];
    int b0 = 0;
    for (int e = 1; e < NE; e++) if (p[e] > p[b0]) b0 = e;
    int b1 = (b0 == 0) ? 1 : 0;
    for (int e = 0; e < NE; e++) if (e != b0 && p[e] > p[b1]) b1 = e;
    int pos0 = atomicAdd(&cur[b0], 1);
    assign[b0 * BT + pos0] = t * 2 + 0;
    int pos1 = atomicAdd(&cur[b1], 1);
    assign[b1 * BT + pos1] = t * 2 + 1;
  }
}

// -------- transpose+convert: src fp32 [E][R][C] -> dst bf16 [E][C][R] --------
// Also zeros cur[] (runs before k_prep_router in stream order).
__global__ __launch_bounds__(256) void k_transpose(const float* __restrict__ src,
                                                   ushort_t* __restrict__ dst,
                                                   int R, int C,
                                                   int* __restrict__ cur) {
  if (cur && blockIdx.x == 0 && blockIdx.y == 0 && blockIdx.z == 0 &&
      threadIdx.x < NE)
    cur[threadIdx.x] = 0;
  __shared__ float tile[64][65];
  int e = blockIdx.z;
  const float* s = src + (size_t)e * R * C;
  ushort_t* d = dst + (size_t)e * R * C;
  int c0 = blockIdx.x * 64, r0 = blockIdx.y * 64;
  int t = threadIdx.x;
  int lr = t >> 4;
  int lc4 = (t & 15) * 4;
#pragma unroll
  for (int i = 0; i < 4; i++) {
    int r = lr + 16 * i;
    float4 v = *(const float4*)&s[(size_t)(r0 + r) * C + c0 + lc4];
    tile[r][lc4 + 0] = v.x; tile[r][lc4 + 1] = v.y;
    tile[r][lc4 + 2] = v.z; tile[r][lc4 + 3] = v.w;
  }
  __syncthreads();
  int c = t >> 3, r8 = (t & 7) * 8;
#pragma unroll
  for (int p = 0; p < 2; p++) {
    int cc = c + 32 * p;
    short8v ov;
#pragma unroll
    for (int i = 0; i < 8; i++) ov[i] = (short)f2bf(tile[r8 + i][cc]);
    *(short8v*)&d[(size_t)(c0 + cc) * R + r0 + r8] = ov;
  }
}

// -------- plan: prefix offsets + flattened active 128-row block list --------
__global__ void k_plan(const int* __restrict__ cur, int* __restrict__ segoff,
                       int* __restrict__ blk_e, int* __restrict__ blk_m0) {
  if (threadIdx.x == 0 && blockIdx.x == 0) {
    int s = 0;
    for (int e = 0; e < NE; e++) { segoff[e] = s; s += cur[e]; }
    int t = 0;
    for (int e = 0; e < NE; e++) {
      int mb = (cur[e] + 127) >> 7;
      for (int i = 0; i < mb; i++) { blk_e[t] = e; blk_m0[t] = i << 7; t++; }
    }
    for (; t < TMX; t++) { blk_e[t] = -1; blk_m0[t] = 0; }
  }
}

// ============================================================================
// GEMM core (R12): 128x128 tile, BK=32, RING-3 LDS = 48 KiB -> 3 blocks/CU,
// 512 thr = 8 waves (2M x 4N), wave tile 64x32, acc[4][2].
// -> 24 waves/CU = 6 waves/SIMD (R11's occupancy lever, continued: 2->4
// waves/SIMD gave -15% gemm time; LDS was the binding resource).
// Per K-tile (discipline = R7/R11, 5x harness-verified):
//   reads(t, slot t%3) -> STAGE(t+2 -> slot (t+2)%3) -> vmcnt(2) ->
//   barrier (publishes t+1) -> sched_barrier -> setprio -> 8 MFMA -> setprio
// Ring-3 slot safety: STAGE(t+2) overwrites slot (t+2)%3 == (t-1)%3 — the
// SAME "overwrite t-1's slot from TILEK(t)" pattern as ring-4's STAGE(t+3)
// ((t+3)&3==(t-1)&3); only prefetch depth changes (2 tiles ≈ 1000cyc cover).
// vmcnt ledger (2 loads/tile/wave): steady vmcnt(2); tail 2,0,none.
// ============================================================================
#define VM2 asm volatile("s_waitcnt vmcnt(2)" ::: "memory")
#define VM0 asm volatile("s_waitcnt vmcnt(0)" ::: "memory")
#define VMN do {} while (0)

#define TILEK(TB, T, VMX, DOSTG)                                                \
  { short8v bv[2], af[4];                                                       \
    _Pragma("unroll")                                                           \
    for (int n = 0; n < 2; n++)                                                 \
      bv[n] = *(const short8v*)&Bv[TB][wn * 32 + n * 16 + lr][xsw];             \
    _Pragma("unroll")                                                           \
    for (int m = 0; m < 4; m++)                                                 \
      af[m] = *(const short8v*)&A[TB][wm * 64 + m * 16 + lr][xsw];              \
    if (DOSTG) { STAGE((((TB) + 2) % 3), ((T) + 2) * 32); }                     \
    VMX;                                                                        \
    __builtin_amdgcn_s_barrier();                                               \
    __builtin_amdgcn_sched_barrier(0);                                          \
    __builtin_amdgcn_s_setprio(1);                                              \
    _Pragma("unroll")                                                           \
    for (int m = 0; m < 4; m++)                                                 \
      _Pragma("unroll")                                                         \
      for (int n = 0; n < 2; n++)                                               \
        acc[m][n] = __builtin_amdgcn_mfma_f32_16x16x32_bf16(af[m], bv[n],       \
                                                            acc[m][n], 0, 0, 0);\
    __builtin_amdgcn_s_setprio(0); }

// ============================================================================
// GEMM1: h = gelu(x_gathered @ w1^T + b1).  Grid 32n x TMX(72)m = 2304.
// 3 blocks/CU -> exactly 3 dispatch rounds of 768.
// ============================================================================
__global__ __launch_bounds__(512, 6) void k_gemm1(
    const ushort_t* __restrict__ xbf, const ushort_t* __restrict__ wt1,
    const float* __restrict__ b1,
    const int* __restrict__ assign, const int* __restrict__ cur,
    const int* __restrict__ segoff, const int* __restrict__ blk_e,
    const int* __restrict__ blk_m0, ushort_t* __restrict__ hbuf) {
  const int nwg = 32 * TMX;                    // 2304, divisible by 8
  int f = blockIdx.x;
  int lg = (f & 7) * (nwg >> 3) + (f >> 3);    // XCD chunk swizzle (bijective)
  int m_idx = lg % TMX;                        // m-inner: chunk reuses B-panels
  int n_idx = lg / TMX;
  int e = blk_e[m_idx];
  if (e < 0) return;
  int m0 = blk_m0[m_idx];
  int count = cur[e];
  int n0 = n_idx << 7;

  __shared__ __attribute__((aligned(16))) ushort_t A[3][128][32];
  __shared__ __attribute__((aligned(16))) ushort_t Bv[3][128][32];
  int tid = threadIdx.x;
  int lane = tid & 63, wid = tid >> 6;

  int srow = lane >> 2;                        // 0..15 within wave's 16 rows
  int sunit = ((lane & 3) ^ ((lane >> 3) & 3)) << 3;
  int pA0 = m0 + wid * 16 + srow;
  int tok0 = (pA0 < count) ? (assign[e * BT + pA0] >> 1) : 0;
  const ushort_t* gA0 = xbf + (size_t)tok0 * DIM + sunit;
  const ushort_t* gB0 = wt1 + ((size_t)e * HID + n0 + wid * 16 + srow) * DIM + sunit;

  int wm = wid >> 2, wn = wid & 3;             // wave tile: 64(m) x 32(n)
  int lr = lane & 15, g = lane >> 4;
  int xsw = ((g ^ ((lr >> 1) & 3)) << 3);
  f32x4 acc[4][2];
  f32x4 zero = {0.f, 0.f, 0.f, 0.f};
#pragma unroll
  for (int m = 0; m < 4; m++)
#pragma unroll
    for (int n = 0; n < 2; n++) acc[m][n] = zero;

#define STAGE(SL, K0)                                          \
  { GLOAD_LDS16(gA0 + (K0), &A[SL][wid * 16][0]);              \
    GLOAD_LDS16(gB0 + (K0), &Bv[SL][wid * 16][0]); }

  STAGE(0, 0);
  STAGE(1, 32);
  VM2;
  __builtin_amdgcn_s_barrier();
  __builtin_amdgcn_sched_barrier(0);

  const int NT = DIM / 32;                     // 32
  for (int t = 0; t < NT - 2; t += 3) {        // t = 0,3,...,27
    TILEK(0, t + 0, VM2, 1);
    TILEK(1, t + 1, VM2, 1);
    TILEK(2, t + 2, VM2, 1);
  }
  TILEK(0, NT - 2, VM0, 0);                    // tile 30, slot 0
  TILEK(1, NT - 1, VMN, 0);                    // tile 31, slot 1
#undef STAGE

  int so = segoff[e];
#pragma unroll
  for (int m = 0; m < 4; m++) {
#pragma unroll
    for (int j = 0; j < 4; j++) {
      int p = m0 + wm * 64 + m * 16 + g * 4 + j;
      if (p >= count) continue;
      ushort_t* hr = hbuf + (size_t)(so + p) * HID;
#pragma unroll
      for (int n = 0; n < 2; n++) {
        int col = n0 + wn * 32 + n * 16 + lr;
        float v = acc[m][n][j] + b1[e * HID + col];
        float gl = 0.5f * v * (1.0f + erff(v * 0.70710678118654752f));
        hr[col] = f2bf(gl);
      }
    }
  }
}

// ============================================================================
// GEMM2: contrib[slot][t] = h @ w2^T + b2.  Grid 8n x TMX(72)m = 576.
// 576 <= 768 -> the whole grid is co-resident (single dispatch round).
// ============================================================================
__global__ __launch_bounds__(512, 6) void k_gemm2(
    const ushort_t* __restrict__ hbuf, const ushort_t* __restrict__ wt2,
    const float* __restrict__ b2,
    const int* __restrict__ assign, const int* __restrict__ cur,
    const int* __restrict__ segoff, const int* __restrict__ blk_e,
    const int* __restrict__ blk_m0, float* __restrict__ contrib) {
  const int nwg = 8 * TMX;                     // 576, divisible by 8
  int f = blockIdx.x;
  int lg = (f & 7) * (nwg >> 3) + (f >> 3);
  int m_idx = lg % TMX;
  int n_idx = lg / TMX;
  int e = blk_e[m_idx];
  if (e < 0) return;
  int m0 = blk_m0[m_idx];
  int count = cur[e];
  int n0 = n_idx << 7;
  int so = segoff[e];

  __shared__ __attribute__((aligned(16))) ushort_t A[3][128][32];
  __shared__ __attribute__((aligned(16))) ushort_t Bv[3][128][32];
  int tid = threadIdx.x;
  int lane = tid & 63, wid = tid >> 6;

  int srow = lane >> 2;
  int sunit = ((lane & 3) ^ ((lane >> 3) & 3)) << 3;
  int pA0 = m0 + wid * 16 + srow;
  int pa0 = (pA0 < count) ? pA0 : (count - 1);
  const ushort_t* gA0 = hbuf + (size_t)(so + pa0) * HID + sunit;
  const ushort_t* gB0 = wt2 + ((size_t)e * DIM + n0 + wid * 16 + srow) * HID + sunit;

  int wm = wid >> 2, wn = wid & 3;             // wave tile: 64(m) x 32(n)
  int lr = lane & 15, g = lane >> 4;
  int xsw = ((g ^ ((lr >> 1) & 3)) << 3);
  f32x4 acc[4][2];
  f32x4 zero = {0.f, 0.f, 0.f, 0.f};
#pragma unroll
  for (int m = 0; m < 4; m++)
#pragma unroll
    for (int n = 0; n < 2; n++) acc[m][n] = zero;

#define STAGE(SL, K0)                                          \
  { GLOAD_LDS16(gA0 + (K0), &A[SL][wid * 16][0]);              \
    GLOAD_LDS16(gB0 + (K0), &Bv[SL][wid * 16][0]); }

  STAGE(0, 0);
  STAGE(1, 32);
  VM2;
  __builtin_amdgcn_s_barrier();
  __builtin_amdgcn_sched_barrier(0);

  const int NT = HID / 32;                     // 128
  for (int t = 0; t < NT - 2; t += 3) {        // t = 0,3,...,123
    TILEK(0, t + 0, VM2, 1);
    TILEK(1, t + 1, VM2, 1);
    TILEK(2, t + 2, VM2, 1);
  }
  TILEK(0, NT - 2, VM0, 0);                    // tile 126, slot 0
  TILEK(1, NT - 1, VMN, 0);                    // tile 127, slot 1
#undef STAGE

#pragma unroll
  for (int m = 0; m < 4; m++) {
#pragma unroll
    for (int j = 0; j < 4; j++) {
      int p = m0 + wm * 64 + m * 16 + g * 4 + j;
      if (p >= count) continue;
      int a = assign[e * BT + p];
      int t = a >> 1, slot = a & 1;
      float* cr = contrib + ((size_t)slot * BT + t) * DIM;
#pragma unroll
      for (int n = 0; n < 2; n++) {
        int col = n0 + wn * 32 + n * 16 + lr;
        cr[col] = acc[m][n][j] + b2[e * DIM + col];
      }
    }
  }
}

// -------- combine: final = c0*probs[:,0] + c1*probs[:,1] --------
__global__ void k_combine(const float* __restrict__ contrib,
                          const float* __restrict__ probs01,
                          float* __restrict__ out) {
  int idx = blockIdx.x * blockDim.x + threadIdx.x;
  const int n4 = BT * DIM / 4;
  if (idx >= n4) return;
  int t = idx >> 8;
  float wA = probs01[t * 2 + 0], wB = probs01[t * 2 + 1];
  float4 c0 = ((const float4*)contrib)[idx];
  float4 c1 = ((const float4*)(contrib + (size_t)BT * DIM))[idx];
  float4 o;
  o.x = c0.x * wA + c1.x * wB;
  o.y = c0.y * wA + c1.y * wB;
  o.z = c0.z * wA + c1.z * wB;
  o.w = c0.w * wA + c1.w * wB;
  ((float4*)out)[idx] = o;
}

extern "C" void kernel_launch(void* const* d_in, const int* in_sizes, int n_in,
                              void* d_out, int out_size, void* d_ws, size_t ws_size,
                              hipStream_t stream) {
  const float* x  = (const float*)d_in[0];
  const float* wg = (const float*)d_in[1];
  const float* w1 = (const float*)d_in[2];
  const float* b1 = (const float*)d_in[3];
  const float* w2 = (const float*)d_in[4];
  const float* b2 = (const float*)d_in[5];
  float* out = (float*)d_out;
  float* logits_out = out + (size_t)BT * DIM;

  char* ws = (char*)d_ws;
  size_t off = 0;
  auto alloc = [&](size_t bytes) -> void* {
    void* p = ws + off;
    off = (off + bytes + 255) & ~(size_t)255;
    return p;
  };
  ushort_t* xbf    = (ushort_t*)alloc((size_t)BT * DIM * 2);
  ushort_t* wt1    = (ushort_t*)alloc((size_t)NE * HID * DIM * 2);
  ushort_t* wt2    = (ushort_t*)alloc((size_t)NE * DIM * HID * 2);
  ushort_t* hbuf   = (ushort_t*)alloc((size_t)2 * BT * HID * 2);
  float*    contrib= (float*)alloc((size_t)2 * BT * DIM * 4);
  float*    probs01= (float*)alloc((size_t)BT * 2 * 4);
  int*      assign = (int*)alloc((size_t)NE * BT * 4);
  int*      cur    = (int*)alloc(64);
  int*      segoff = (int*)alloc(64);
  int*      blk_e  = (int*)alloc(TMX * 4);
  int*      blk_m0 = (int*)alloc(TMX * 4);
  if (off > ws_size) return;

  // transpose(w1) also zeros cur; stream order puts it before k_prep_router.
  hipLaunchKernelGGL(k_transpose, dim3(HID / 64, DIM / 64, NE), dim3(256), 0, stream,
                     w1, wt1, DIM, HID, cur);
  hipLaunchKernelGGL(k_transpose, dim3(DIM / 64, HID / 64, NE), dim3(256), 0, stream,
                     w2, wt2, HID, DIM, (int*)nullptr);
  hipLaunchKernelGGL(k_prep_router, dim3(BT), dim3(256), 0, stream,
                     x, wg, xbf, logits_out, probs01, assign, cur);
  hipLaunchKernelGGL(k_plan, dim3(1), dim3(64), 0, stream, cur, segoff,
                     blk_e, blk_m0);
  hipLaunchKernelGGL(k_gemm1, dim3(32 * TMX), dim3(512), 0, stream,
                     xbf, wt1, b1, assign, cur, segoff, blk_e, blk_m0, hbuf);
  hipLaunchKernelGGL(k_gemm2, dim3(8 * TMX), dim3(512), 0, stream,
                     hbuf, wt2, b2, assign, cur, segoff, blk_e, blk_m0, contrib);
  hipLaunchKernelGGL(k_combine, dim3((BT * DIM / 4 + 255) / 256), dim3(256), 0, stream,
                     contrib, probs01, out);
}